// Round 18
// baseline (474.966 us; speedup 1.0000x reference)
//
#include <hip/hip_runtime.h>
#include <math.h>

#define D 128
#define NN 256
#define NB 2048          // B*N rows of h
#define FF 512

typedef float f32x4 __attribute__((ext_vector_type(4)));
typedef __bf16 bf16x8 __attribute__((ext_vector_type(8)));
typedef unsigned int u32x4 __attribute__((ext_vector_type(4)));

__device__ __forceinline__ float gelu_f(float x) {
  float x3 = x * x * x;
  float u = 0.7978845608028654f * (x + 0.044715f * x3);
  return 0.5f * x * (1.0f + tanhf(u));
}

__device__ __forceinline__ bf16x8 cvt8(f32x4 a, f32x4 b) {
  bf16x8 r;
  r[0] = (__bf16)a.x; r[1] = (__bf16)a.y; r[2] = (__bf16)a.z; r[3] = (__bf16)a.w;
  r[4] = (__bf16)b.x; r[5] = (__bf16)b.y; r[6] = (__bf16)b.z; r[7] = (__bf16)b.w;
  return r;
}

__device__ __forceinline__ float sigmoid_f(float v) {
  float ex = __builtin_amdgcn_exp2f(-1.44269504f * v);
  return __builtin_amdgcn_rcpf(1.0f + ex);
}

// bf16-pair pack/unpack
__device__ __forceinline__ unsigned int packbf(float a, float v) {
  unsigned short ha = __builtin_bit_cast(unsigned short, (__bf16)a);
  unsigned short hv = __builtin_bit_cast(unsigned short, (__bf16)v);
  return (unsigned int)ha | ((unsigned int)hv << 16);
}
__device__ __forceinline__ float bflo(unsigned int u) {
  return __builtin_bit_cast(float, u << 16);
}
__device__ __forceinline__ float bfhi(unsigned int u) {
  return __builtin_bit_cast(float, u & 0xffff0000u);
}

// ---------------------------------------------------------------------------
// K0: pack Cw [128k x 128d] into bf16 MFMA fragment order.
// ---------------------------------------------------------------------------
__global__ __launch_bounds__(256) void k0_pack(const float* __restrict__ Cw,
                                               __bf16* __restrict__ ws0) {
  int tid = blockIdx.x * 256 + threadIdx.x;  // nt*256 + ks*64 + l
  int l  = tid & 63;
  int nt = tid >> 8;
  int ks = (tid >> 6) & 3;
  int d  = nt * 16 + (l & 15);
  int kb = ks * 32 + (l >> 4) * 8;
  bf16x8 v;
#pragma unroll
  for (int q = 0; q < 8; ++q) v[q] = (__bf16)Cw[(kb + q) * D + d];
  *(bf16x8*)(ws0 + tid * 8) = v;
}

// ---------------------------------------------------------------------------
// K1: Uh/Vh/Ah/(Bh+Cb) = h @ {U,V,A,B}w + bias.  R18: 8 rows per block
// (grid 256) -- each weight column load serves 8 register accumulators,
// cutting weight L2 traffic 8x (512MB -> 64MB).
// ---------------------------------------------------------------------------
__global__ __launch_bounds__(256) void k1_lin4(
    const float* __restrict__ h,
    const float* __restrict__ Uw, const float* __restrict__ Ub,
    const float* __restrict__ Vw, const float* __restrict__ Vb,
    const float* __restrict__ Aw, const float* __restrict__ Ab,
    const float* __restrict__ Bw, const float* __restrict__ Bb,
    const float* __restrict__ Cb,
    float* __restrict__ wsU, float* __restrict__ wsB,
    unsigned int* __restrict__ wsAVT, unsigned int* __restrict__ wsAVR) {
  __shared__ float hrow[8][128];
  __shared__ float exA[8][128];
  __shared__ float exV[8][128];
  const int rbase = blockIdx.x * 8;
  const int t = threadIdx.x;
#pragma unroll
  for (int q = 0; q < 4; ++q) {
    int idx = q * 256 + t;
    int rr = idx >> 7, dd = idx & 127;
    hrow[rr][dd] = h[(rbase + rr) * D + dd];
  }
  __syncthreads();
  const int d = t & 127;
  const bool lo = (t < 128);
  const float* W0 = lo ? Uw : Vw;
  const float* W1m = lo ? Aw : Bw;
  const float base0 = (lo ? Ub : Vb)[d];
  const float base1 = lo ? Ab[d] : (Bb[d] + Cb[d]);
  float a0[8], a1[8];
#pragma unroll
  for (int r = 0; r < 8; ++r) { a0[r] = base0; a1[r] = base1; }
#pragma unroll 2
  for (int k = 0; k < D; ++k) {
    float w0v = W0[k * D + d];
    float w1v = W1m[k * D + d];
#pragma unroll
    for (int r = 0; r < 8; ++r) {
      float hk = hrow[r][k];
      a0[r] = fmaf(hk, w0v, a0[r]);
      a1[r] = fmaf(hk, w1v, a1[r]);
    }
  }
#pragma unroll
  for (int r = 0; r < 8; ++r) {
    int row = rbase + r;
    if (lo) {
      wsU[row * D + d] = a0[r];
      exA[r][d] = a1[r];
    } else {
      exV[r][d] = a0[r];
      wsB[row * D + d] = a1[r];
    }
  }
  __syncthreads();
#pragma unroll
  for (int q = 0; q < 4; ++q) {
    int idx = q * 256 + t;
    int rr = idx >> 7, dd = idx & 127;
    int row = rbase + rr;
    int b = row >> 8, i = row & 255;
    unsigned int p = packbf(exA[rr][dd], exV[rr][dd]);
    wsAVR[row * D + dd] = p;               // row-major
    wsAVT[(b << 15) + dd * NN + i] = p;    // transposed (fallback)
  }
}

// ---------------------------------------------------------------------------
// K2 (big path): PURE GEMM: ws1 = bf16(e @ Cw).  R17-proven: bfr LDS
// staging, stride-66 stW, full-tile 4KB stores, 3 blocks/CU, 2-deep
// e-prefetch (pfA/pfB ping-pong).
// ---------------------------------------------------------------------------
__global__ __launch_bounds__(256, 3) void k_gemm(
    const float* __restrict__ e,
    const __bf16* __restrict__ ws0,
    __bf16* __restrict__ ws1) {
  __shared__ __align__(16) __bf16 bfr[16384];        // 32 KB Cw fragments
  __shared__ __align__(16) unsigned int stW[4224];   // [4][16][66] u32
  const int t = threadIdx.x;
  const int blk = blockIdx.x;

#pragma unroll
  for (int c = 0; c < 8; ++c) {
    int idx = c * 256 + t;
    *(f32x4*)(bfr + idx * 8) = *(const f32x4*)(ws0 + idx * 8);
  }
  __syncthreads();

  const int w = t >> 6;
  const int l = t & 63;
  const int l15 = l & 15;
  const int lhi = l >> 4;
  unsigned int* stWu = stW + w * 1056;  // [16][66]

  const float* eblk = e + (size_t)blk * (NN * D);
  const float* ap = eblk + (w * 64 + l15) * D + lhi * 8;

  // 2-deep prefetch: pfA=tile0, pfB=tile1
  f32x4 pfA[8], pfB[8];
#pragma unroll
  for (int q = 0; q < 8; ++q) pfA[q] = *(const f32x4*)(ap + (q >> 1) * 32 + (q & 1) * 4);
#pragma unroll
  for (int q = 0; q < 8; ++q) pfB[q] = *(const f32x4*)(ap + 16 * D + (q >> 1) * 32 + (q & 1) * 4);

  auto do_tile = [&](const f32x4* pf, int mt) {
    bf16x8 af[4];
#pragma unroll
    for (int ks = 0; ks < 4; ++ks) af[ks] = cvt8(pf[2 * ks], pf[2 * ks + 1]);
    const int J0 = w * 64 + mt * 16;
#pragma unroll
    for (int nt = 0; nt < 8; ++nt) {
      f32x4 acc = {0.f, 0.f, 0.f, 0.f};
#pragma unroll
      for (int ks = 0; ks < 4; ++ks) {
        bf16x8 bfrg = *(const bf16x8*)(bfr + ((nt * 4 + ks) * 64 + l) * 8);
        acc = __builtin_amdgcn_mfma_f32_16x16x32_bf16(af[ks], bfrg, acc, 0, 0, 0);
      }
#pragma unroll
      for (int r = 0; r < 4; ++r) {
        float v = acc[r];
        float vp = __shfl_xor(v, 1);  // partner lane holds d^1
        if ((l15 & 1) == 0) {
          stWu[(lhi * 4 + r) * 66 + (nt << 3) + (l15 >> 1)] = packbf(v, vp);
        }
      }
    }
    // coalesced u32 store of the 16x128 bf16 tile (4KB contiguous)
    unsigned int* dstu = (unsigned int*)(ws1 + (size_t)blk * (NN * D) + J0 * D);
#pragma unroll
    for (int i = 0; i < 16; ++i) {
      dstu[i * 64 + l] = stWu[i * 66 + l];
    }
  };

  // tile 0 (pfA), refill pfA <- tile 2
  {
    f32x4 cur[8];
#pragma unroll
    for (int q = 0; q < 8; ++q) cur[q] = pfA[q];
#pragma unroll
    for (int q = 0; q < 8; ++q) pfA[q] = *(const f32x4*)(ap + 32 * D + (q >> 1) * 32 + (q & 1) * 4);
    do_tile(cur, 0);
  }
  // tile 1 (pfB), refill pfB <- tile 3
  {
    f32x4 cur[8];
#pragma unroll
    for (int q = 0; q < 8; ++q) cur[q] = pfB[q];
#pragma unroll
    for (int q = 0; q < 8; ++q) pfB[q] = *(const f32x4*)(ap + 48 * D + (q >> 1) * 32 + (q & 1) * 4);
    do_tile(cur, 1);
  }
  do_tile(pfA, 2);
  do_tile(pfB, 3);
}

// ---------------------------------------------------------------------------
// K2b (big path): streaming stats + gated aggregation from ws1 (R13 form).
// ---------------------------------------------------------------------------
__global__ __launch_bounds__(256) void k_stats(
    const __bf16* __restrict__ ws1,
    const unsigned int* __restrict__ AVR,   // [b*256+j][d] packed Ah|Vh
    const float* __restrict__ Bh2,          // Bh + Cb
    float* __restrict__ wsP) {
  __shared__ float red[16][3][128];
  const int t = threadIdx.x;
  const int blk = blockIdx.x;
  const int b = blk >> 8;
  const int jg = t >> 4;
  const int dg = t & 15;

  float cb[8];
  {
    f32x4 c0 = *(const f32x4*)(Bh2 + blk * D + dg * 8);
    f32x4 c1 = *(const f32x4*)(Bh2 + blk * D + dg * 8 + 4);
#pragma unroll
    for (int q = 0; q < 4; ++q) { cb[q] = c0[q]; cb[4 + q] = c1[q]; }
  }

  float es[8], eq[8], hp[8];
#pragma unroll
  for (int q = 0; q < 8; ++q) { es[q] = 0.f; eq[q] = 0.f; hp[q] = 0.f; }

  const unsigned int* w1 = (const unsigned int*)(ws1 + (size_t)blk * (NN * D));
  const unsigned int* avb = AVR + ((size_t)(b << 8)) * D;

#pragma unroll 1
  for (int k = 0; k < 16; ++k) {
    const int j = k * 16 + jg;
    u32x4 a = *(const u32x4*)(w1 + j * 64 + dg * 4);          // 8 bf16 e_new
    u32x4 av0 = *(const u32x4*)(avb + j * D + dg * 8);        // d0..d3
    u32x4 av1 = *(const u32x4*)(avb + j * D + dg * 8 + 4);    // d4..d7
#pragma unroll
    for (int q = 0; q < 4; ++q) {
      unsigned int avA = (q < 2) ? av0[2 * q] : av1[2 * (q - 2)];
      unsigned int avB = (q < 2) ? av0[2 * q + 1] : av1[2 * (q - 2) + 1];
      float v0 = bflo(a[q]) + cb[2 * q] + bflo(avA);
      float v1 = bfhi(a[q]) + cb[2 * q + 1] + bflo(avB);
      es[2 * q] += v0;
      eq[2 * q] = fmaf(v0, v0, eq[2 * q]);
      hp[2 * q] = fmaf(sigmoid_f(v0), bfhi(avA), hp[2 * q]);
      es[2 * q + 1] += v1;
      eq[2 * q + 1] = fmaf(v1, v1, eq[2 * q + 1]);
      hp[2 * q + 1] = fmaf(sigmoid_f(v1), bfhi(avB), hp[2 * q + 1]);
    }
  }

#pragma unroll
  for (int q = 0; q < 8; ++q) {
    red[jg][0][dg * 8 + q] = es[q];
    red[jg][1][dg * 8 + q] = eq[q];
    red[jg][2][dg * 8 + q] = hp[q];
  }
  __syncthreads();
  if (t < 128) {
    float S = 0.f, Q = 0.f, H = 0.f;
#pragma unroll
    for (int g = 0; g < 16; ++g) {
      S += red[g][0][t];
      Q += red[g][1][t];
      H += red[g][2][t];
    }
    wsP[blk * 384 + t] = S;
    wsP[blk * 384 + 128 + t] = Q;
    wsP[blk * 384 + 256 + t] = H;
  }
}

// ---------------------------------------------------------------------------
// K5 (big path, streaming): out_e = relu(ge*(ws1+cb+ah) + be) + e.
// ---------------------------------------------------------------------------
__global__ __launch_bounds__(256) void k_epass1s(
    const __bf16* __restrict__ ws1,
    const float* __restrict__ e,
    const unsigned int* __restrict__ AVR,
    const float* __restrict__ Bh2,
    const float* __restrict__ ws6,   // [0:128) ge, [128:256) be
    float* __restrict__ out_e) {
  const int tid = blockIdx.x * 256 + threadIdx.x;
  const int d0 = (tid & 15) * 8;
  f32x4 ge0 = *(const f32x4*)(ws6 + d0);
  f32x4 ge1 = *(const f32x4*)(ws6 + d0 + 4);
  f32x4 be0 = *(const f32x4*)(ws6 + 128 + d0);
  f32x4 be1 = *(const f32x4*)(ws6 + 128 + d0 + 4);
#pragma unroll 2
  for (int k = 0; k < 16; ++k) {
    size_t idx = (size_t)tid + (size_t)k * 524288;  // vec8 index
    size_t row = idx >> 4;                 // b*65536 + i*256 + j
    int j = (int)(row & 255);
    int bb = (int)(row >> 16);
    size_t avrow = ((size_t)(bb << 8) + j);
    u32x4 u = *(const u32x4*)(ws1 + idx * 8);
    u32x4 av0 = *(const u32x4*)(AVR + avrow * D + d0);
    u32x4 av1 = *(const u32x4*)(AVR + avrow * D + d0 + 4);
    const float* cbp = Bh2 + (row >> 8) * D + d0;
    f32x4 c0 = *(const f32x4*)cbp;
    f32x4 c1 = *(const f32x4*)(cbp + 4);
    const float* ep = e + idx * 8;
    f32x4 e0 = *(const f32x4*)ep;
    f32x4 e1 = *(const f32x4*)(ep + 4);
    f32x4 o0, o1;
#pragma unroll
    for (int q = 0; q < 2; ++q) {
      float v0 = bflo(u[q]) + c0[2 * q] + bflo(av0[2 * q]);
      float v1 = bfhi(u[q]) + c0[2 * q + 1] + bflo(av0[2 * q + 1]);
      o0[2 * q]     = fmaxf(fmaf(v0, ge0[2 * q], be0[2 * q]), 0.f) + e0[2 * q];
      o0[2 * q + 1] = fmaxf(fmaf(v1, ge0[2 * q + 1], be0[2 * q + 1]), 0.f) + e0[2 * q + 1];
      float v2 = bflo(u[2 + q]) + c1[2 * q] + bflo(av1[2 * q]);
      float v3 = bfhi(u[2 + q]) + c1[2 * q + 1] + bflo(av1[2 * q + 1]);
      o1[2 * q]     = fmaxf(fmaf(v2, ge1[2 * q], be1[2 * q]), 0.f) + e1[2 * q];
      o1[2 * q + 1] = fmaxf(fmaf(v3, ge1[2 * q + 1], be1[2 * q + 1]), 0.f) + e1[2 * q + 1];
    }
    float* op = out_e + idx * 8;
    *(f32x4*)op = o0;
    *(f32x4*)(op + 4) = o1;
  }
}

// ---------------------------------------------------------------------------
// FALLBACK kernels (small ws): fused epass0 + recompute epass1 (AVT layout).
// ---------------------------------------------------------------------------
__global__ __launch_bounds__(256, 3) void k_epass0_fused(
    const float* __restrict__ e,
    const __bf16* __restrict__ ws0,
    const unsigned int* __restrict__ AVT,
    const float* __restrict__ Bh2,
    float* __restrict__ wsP) {
  __shared__ __align__(16) __bf16 bfr[16384];
  __shared__ __align__(16) unsigned int uni32[4224];
  const int t = threadIdx.x;
  const int blk = blockIdx.x;
  const int b = blk >> 8;

#pragma unroll
  for (int c = 0; c < 8; ++c) {
    int idx = c * 256 + t;
    *(f32x4*)(bfr + idx * 8) = *(const f32x4*)(ws0 + idx * 8);
  }
  __syncthreads();

  const int w = t >> 6;
  const int l = t & 63;
  const int l15 = l & 15;
  const int lhi = l >> 4;

  float cbias[8];
#pragma unroll
  for (int nt = 0; nt < 8; ++nt) cbias[nt] = Bh2[blk * D + nt * 16 + l15];

  float es[8], eq[8], hp[8];
#pragma unroll
  for (int nt = 0; nt < 8; ++nt) { es[nt] = 0.f; eq[nt] = 0.f; hp[nt] = 0.f; }

  const float* eblk = e + (size_t)blk * (NN * D);
  const unsigned int* AVb = AVT + ((size_t)b << 15);

  const float* ap = eblk + (w * 64 + l15) * D + lhi * 8;
  f32x4 pf[8];
#pragma unroll
  for (int q = 0; q < 8; ++q) pf[q] = *(const f32x4*)(ap + (q >> 1) * 32 + (q & 1) * 4);

#pragma unroll 1
  for (int mt = 0; mt < 4; ++mt) {
    bf16x8 af[4];
#pragma unroll
    for (int ks = 0; ks < 4; ++ks) af[ks] = cvt8(pf[2 * ks], pf[2 * ks + 1]);
    if (mt < 3) {
      const float* ap2 = ap + (mt + 1) * 16 * D;
#pragma unroll
      for (int q = 0; q < 8; ++q) pf[q] = *(const f32x4*)(ap2 + (q >> 1) * 32 + (q & 1) * 4);
    }
    const int J0 = w * 64 + mt * 16;
#pragma unroll
    for (int nt = 0; nt < 8; ++nt) {
      f32x4 acc = {0.f, 0.f, 0.f, 0.f};
#pragma unroll
      for (int ks = 0; ks < 4; ++ks) {
        bf16x8 bfrg = *(const bf16x8*)(bfr + ((nt * 4 + ks) * 64 + l) * 8);
        acc = __builtin_amdgcn_mfma_f32_16x16x32_bf16(af[ks], bfrg, acc, 0, 0, 0);
      }
      const int doff = (nt * 16 + l15) * NN + J0 + lhi * 4;
      u32x4 uv = *(const u32x4*)(AVb + doff);
#pragma unroll
      for (int r = 0; r < 4; ++r) {
        float v = acc[r] + cbias[nt] + bflo(uv[r]);
        es[nt] += v;
        eq[nt] = fmaf(v, v, eq[nt]);
        float g = sigmoid_f(v);
        hp[nt] = fmaf(g, bfhi(uv[r]), hp[nt]);
      }
    }
  }

#pragma unroll
  for (int nt = 0; nt < 8; ++nt) {
    es[nt] += __shfl_xor(es[nt], 16); es[nt] += __shfl_xor(es[nt], 32);
    eq[nt] += __shfl_xor(eq[nt], 16); eq[nt] += __shfl_xor(eq[nt], 32);
    hp[nt] += __shfl_xor(hp[nt], 16); hp[nt] += __shfl_xor(hp[nt], 32);
  }
  __syncthreads();
  float* red = (float*)uni32;
  if (l < 16) {
#pragma unroll
    for (int nt = 0; nt < 8; ++nt) {
      red[(w * 3 + 0) * 128 + nt * 16 + l] = es[nt];
      red[(w * 3 + 1) * 128 + nt * 16 + l] = eq[nt];
      red[(w * 3 + 2) * 128 + nt * 16 + l] = hp[nt];
    }
  }
  __syncthreads();
  if (t < 128) {
    float S = red[0 * 128 + t] + red[3 * 128 + t] + red[6 * 128 + t] + red[9 * 128 + t];
    float Q = red[1 * 128 + t] + red[4 * 128 + t] + red[7 * 128 + t] + red[10 * 128 + t];
    float H = red[2 * 128 + t] + red[5 * 128 + t] + red[8 * 128 + t] + red[11 * 128 + t];
    wsP[blk * 384 + t] = S;
    wsP[blk * 384 + 128 + t] = Q;
    wsP[blk * 384 + 256 + t] = H;
  }
}

__global__ __launch_bounds__(256, 3) void k_epass1(
    const float* __restrict__ e,
    const __bf16* __restrict__ ws0,
    const unsigned int* __restrict__ AVT,
    const float* __restrict__ Bh2,
    const float* __restrict__ ws6,
    float* __restrict__ out_e) {
  __shared__ __align__(16) __bf16 bfr[16384];
  __shared__ float st[4][16 * 68];
  const int t = threadIdx.x;
  const int blk = blockIdx.x;
  const int b = blk >> 8;

#pragma unroll
  for (int c = 0; c < 8; ++c) {
    int idx = c * 256 + t;
    *(f32x4*)(bfr + idx * 8) = *(const f32x4*)(ws0 + idx * 8);
  }
  __syncthreads();

  const int w = t >> 6;
  const int l = t & 63;
  const int l15 = l & 15;
  const int lhi = l >> 4;
  float* stw = &st[w][0];

  float cbias[8], ge[8], be[8];
#pragma unroll
  for (int nt = 0; nt < 8; ++nt) {
    int d = nt * 16 + l15;
    cbias[nt] = Bh2[blk * D + d];
    ge[nt] = ws6[d];
    be[nt] = ws6[128 + d];
  }

  const float* eblk = e + (size_t)blk * (NN * D);
  const unsigned int* AVb = AVT + ((size_t)b << 15);
  float* outB = out_e + (size_t)blk * (NN * D);

  const int srow = l >> 4;
  const int scol = (l & 15) * 4;

  const float* ap = eblk + (w * 64 + l15) * D + lhi * 8;
  f32x4 pf[8];
#pragma unroll
  for (int q = 0; q < 8; ++q) pf[q] = *(const f32x4*)(ap + (q >> 1) * 32 + (q & 1) * 4);

#pragma unroll 1
  for (int mt = 0; mt < 4; ++mt) {
    bf16x8 af[4];
#pragma unroll
    for (int ks = 0; ks < 4; ++ks) af[ks] = cvt8(pf[2 * ks], pf[2 * ks + 1]);
    if (mt < 3) {
      const float* ap2 = ap + (mt + 1) * 16 * D;
#pragma unroll
      for (int q = 0; q < 8; ++q) pf[q] = *(const f32x4*)(ap2 + (q >> 1) * 32 + (q & 1) * 4);
    }
    const int J0 = w * 64 + mt * 16;
#pragma unroll
    for (int p = 0; p < 2; ++p) {
#pragma unroll
      for (int ntl = 0; ntl < 4; ++ntl) {
        const int nt = p * 4 + ntl;
        f32x4 acc = {0.f, 0.f, 0.f, 0.f};
#pragma unroll
        for (int ks = 0; ks < 4; ++ks) {
          bf16x8 bfrg = *(const bf16x8*)(bfr + ((nt * 4 + ks) * 64 + l) * 8);
          acc = __builtin_amdgcn_mfma_f32_16x16x32_bf16(af[ks], bfrg, acc, 0, 0, 0);
        }
        const int doff = (nt * 16 + l15) * NN + J0 + lhi * 4;
        u32x4 uv = *(const u32x4*)(AVb + doff);
#pragma unroll
        for (int r = 0; r < 4; ++r) {
          float v = acc[r] + cbias[nt] + bflo(uv[r]);
          stw[(lhi * 4 + r) * 68 + ntl * 16 + l15] =
              fmaxf(fmaf(v, ge[nt], be[nt]), 0.0f);
        }
      }
#pragma unroll
      for (int it = 0; it < 4; ++it) {
        const int row = it * 4 + srow;
        const int goff = (J0 + row) * D + p * 64 + scol;
        f32x4 res = *(const f32x4*)(eblk + goff);
        f32x4 q = *(const f32x4*)(stw + row * 68 + scol);
        *(f32x4*)(outB + goff) = q + res;
      }
    }
  }
}

// ---------------------------------------------------------------------------
// K3a: stage-1 reduce of block partials and h_new = Uh + hsum (to ws7).
// ---------------------------------------------------------------------------
__global__ __launch_bounds__(256) void k3a(const float* __restrict__ wsP,
                                           const float* __restrict__ wsU,
                                           float* __restrict__ ws7,
                                           float* __restrict__ wsPB) {
  __shared__ float red2[2][4][128];
  int t = threadIdx.x, blk = blockIdx.x;
  int c = t & 127, half = t >> 7;
  float es = 0.f, eq = 0.f, hs = 0.f, hq = 0.f;
  for (int s = 0; s < 16; ++s) {
    int row = blk * 32 + half * 16 + s;
    es += wsP[row * 384 + c];
    eq += wsP[row * 384 + 128 + c];
    float v = wsU[row * D + c] + wsP[row * 384 + 256 + c];
    ws7[row * D + c] = v;
    hs += v;
    hq = fmaf(v, v, hq);
  }
  red2[half][0][c] = es; red2[half][1][c] = eq;
  red2[half][2][c] = hs; red2[half][3][c] = hq;
  __syncthreads();
  if (t < 128) {
#pragma unroll
    for (int k = 0; k < 4; ++k)
      wsPB[blk * 512 + k * 128 + t] = red2[0][k][t] + red2[1][k][t];
  }
}

// K3b: final stats -> affine coefficients.
__global__ __launch_bounds__(256) void k3b(const float* __restrict__ wsPB,
                                           const float* __restrict__ gamma_e,
                                           const float* __restrict__ beta_e,
                                           const float* __restrict__ gamma_h,
                                           const float* __restrict__ beta_h,
                                           float* __restrict__ ws6) {
  int t = threadIdx.x;
  int c = t & 127, g = t >> 7;
  float S = 0.f, Q = 0.f;
  for (int blk = 0; blk < 64; ++blk) {
    S += wsPB[blk * 512 + (g * 2) * 128 + c];
    Q += wsPB[blk * 512 + (g * 2 + 1) * 128 + c];
  }
  float M = g ? 2048.0f : 524288.0f;
  float mean = S / M;
  float var = Q / M - mean * mean;
  float rstd = rsqrtf(var + 1e-5f);
  float gam = (g ? gamma_h : gamma_e)[c] * rstd;
  float bet = (g ? beta_h : beta_e)[c] - mean * gam;
  ws6[g * 256 + c] = gam;
  ws6[g * 256 + 128 + c] = bet;
}

// ---------------------------------------------------------------------------
// K4: h-side: BN_h, MLP (gelu), residual.  R18: 8 rows per block (grid 256)
// -- W1/W2 column loads serve 8 register accumulators, cutting weight L2
// traffic 8x (1GB -> 128MB).
// ---------------------------------------------------------------------------
__global__ __launch_bounds__(256) void k4_mlp(
    const float* __restrict__ ws7, const float* __restrict__ ws6,
    const float* __restrict__ W1, const float* __restrict__ b1,
    const float* __restrict__ W2, const float* __restrict__ b2,
    const float* __restrict__ h_in, float* __restrict__ out_h) {
  __shared__ float hn[8][128];
  __shared__ float t1[8][FF];
  const int rbase = blockIdx.x * 8;
  const int t = threadIdx.x;
#pragma unroll
  for (int q = 0; q < 4; ++q) {
    int idx = q * 256 + t;
    int rr = idx >> 7, dd = idx & 127;
    float v = ws7[(rbase + rr) * D + dd];
    hn[rr][dd] = fmaf(v, ws6[256 + dd], ws6[384 + dd]);
  }
  __syncthreads();
  {
    const int f0 = t, f1 = t + 256;
    float a0[8], a1[8];
    const float bb0 = b1[f0], bb1 = b1[f1];
#pragma unroll
    for (int r = 0; r < 8; ++r) { a0[r] = bb0; a1[r] = bb1; }
#pragma unroll 2
    for (int k = 0; k < D; ++k) {
      float w0 = W1[k * FF + f0];
      float w1 = W1[k * FF + f1];
#pragma unroll
      for (int r = 0; r < 8; ++r) {
        float hk = hn[r][k];
        a0[r] = fmaf(hk, w0, a0[r]);
        a1[r] = fmaf(hk, w1, a1[r]);
      }
    }
#pragma unroll
    for (int r = 0; r < 8; ++r) {
      t1[r][f0] = gelu_f(a0[r]);
      t1[r][f1] = gelu_f(a1[r]);
    }
  }
  __syncthreads();
  {
    const int d = t & 127;
    const int rb = (t >> 7) * 4;   // 0 or 4
    float acc[4];
    const float bb = b2[d];
#pragma unroll
    for (int r = 0; r < 4; ++r) acc[r] = bb;
#pragma unroll 2
    for (int k = 0; k < FF; ++k) {
      float w2 = W2[k * D + d];
#pragma unroll
      for (int r = 0; r < 4; ++r) acc[r] = fmaf(t1[rb + r][k], w2, acc[r]);
    }
#pragma unroll
    for (int r = 0; r < 4; ++r) {
      int row = rbase + rb + r;
      out_h[row * D + d] = h_in[row * D + d] + acc[r];
    }
  }
}

// ---------------------------------------------------------------------------
extern "C" void kernel_launch(void* const* d_in, const int* in_sizes, int n_in,
                              void* d_out, int out_size, void* d_ws, size_t ws_size,
                              hipStream_t stream) {
  (void)in_sizes; (void)n_in; (void)out_size;
  const float* h       = (const float*)d_in[0];
  const float* e       = (const float*)d_in[1];
  const float* Uw      = (const float*)d_in[2];
  const float* Ub      = (const float*)d_in[3];
  const float* Vw      = (const float*)d_in[4];
  const float* Vb      = (const float*)d_in[5];
  const float* Aw      = (const float*)d_in[6];
  const float* Ab      = (const float*)d_in[7];
  const float* Bw      = (const float*)d_in[8];
  const float* Bb      = (const float*)d_in[9];
  const float* Cw      = (const float*)d_in[10];
  const float* Cb      = (const float*)d_in[11];
  const float* gamma_h = (const float*)d_in[12];
  const float* beta_h  = (const float*)d_in[13];
  const float* gamma_e = (const float*)d_in[14];
  const float* beta_e  = (const float*)d_in[15];
  const float* W1      = (const float*)d_in[16];
  const float* b1      = (const float*)d_in[17];
  const float* W2      = (const float*)d_in[18];
  const float* b2      = (const float*)d_in[19];

  float* ws   = (float*)d_ws;
  __bf16* ws0 = (__bf16*)ws;                 // 16384 bf16 (8192 f32 slots)
  float* wsU  = ws + 8192;
  float* wsB  = wsU + NB * D;                // Bh + Cb
  unsigned int* wsAVT = (unsigned int*)(wsB + NB * D);   // [b][d][j]
  unsigned int* wsAVR = wsAVT + NB * D;                  // [b*256+j][d]
  float* wsP  = (float*)(wsAVR + NB * D);    // 2048 * 384
  float* wsPB = wsP + NB * 384;              // 64 * 512
  float* ws6  = wsPB + 64 * 512;             // 512 affine coeffs
  float* ws7  = ws6 + 512;                   // h_new 2048*128
  size_t head_bytes = (size_t)(ws7 + NB * D - ws) * 4;
  head_bytes = (head_bytes + 255) & ~(size_t)255;
  __bf16* ws1 = (__bf16*)((char*)d_ws + head_bytes);
  size_t need = head_bytes + (size_t)NB * NN * D * 2;
  bool big = (ws_size >= need);

  float* out_h = (float*)d_out;
  float* out_e = out_h + NB * D;

  k0_pack<<<dim3(8), dim3(256), 0, stream>>>(Cw, ws0);
  k1_lin4<<<dim3(NB / 8), dim3(256), 0, stream>>>(h, Uw, Ub, Vw, Vb, Aw, Ab, Bw, Bb,
                                                  Cb, wsU, wsB, wsAVT, wsAVR);
  if (big) {
    k_gemm<<<dim3(NB), dim3(256), 0, stream>>>(e, ws0, ws1);
    k_stats<<<dim3(NB), dim3(256), 0, stream>>>(ws1, wsAVR, wsB, wsP);
  } else {
    k_epass0_fused<<<dim3(NB), dim3(256), 0, stream>>>(e, ws0, wsAVT, wsB, wsP);
  }
  k3a<<<dim3(64), dim3(256), 0, stream>>>(wsP, wsU, ws7, wsPB);
  k3b<<<dim3(1), dim3(256), 0, stream>>>(wsPB, gamma_e, beta_e, gamma_h, beta_h, ws6);
  k4_mlp<<<dim3(NB / 8), dim3(256), 0, stream>>>(ws7, ws6, W1, b1, W2, b2, h, out_h);
  if (big) {
    k_epass1s<<<dim3(2048), dim3(256), 0, stream>>>(ws1, e, wsAVR, wsB, ws6, out_e);
  } else {
    k_epass1<<<dim3(NB), dim3(256), 0, stream>>>(e, ws0, wsAVT, wsB, ws6, out_e);
  }
}

// Round 19
// 380.930 us; speedup vs baseline: 1.2469x; 1.2469x over previous
//
#include <hip/hip_runtime.h>
#include <math.h>

#define D 128
#define NN 256
#define NB 2048          // B*N rows of h
#define FF 512

typedef float f32x4 __attribute__((ext_vector_type(4)));
typedef __bf16 bf16x8 __attribute__((ext_vector_type(8)));
typedef unsigned int u32x4 __attribute__((ext_vector_type(4)));

__device__ __forceinline__ float gelu_f(float x) {
  float x3 = x * x * x;
  float u = 0.7978845608028654f * (x + 0.044715f * x3);
  return 0.5f * x * (1.0f + tanhf(u));
}

__device__ __forceinline__ bf16x8 cvt8(f32x4 a, f32x4 b) {
  bf16x8 r;
  r[0] = (__bf16)a.x; r[1] = (__bf16)a.y; r[2] = (__bf16)a.z; r[3] = (__bf16)a.w;
  r[4] = (__bf16)b.x; r[5] = (__bf16)b.y; r[6] = (__bf16)b.z; r[7] = (__bf16)b.w;
  return r;
}

__device__ __forceinline__ float sigmoid_f(float v) {
  float ex = __builtin_amdgcn_exp2f(-1.44269504f * v);
  return __builtin_amdgcn_rcpf(1.0f + ex);
}

// bf16-pair pack/unpack
__device__ __forceinline__ unsigned int packbf(float a, float v) {
  unsigned short ha = __builtin_bit_cast(unsigned short, (__bf16)a);
  unsigned short hv = __builtin_bit_cast(unsigned short, (__bf16)v);
  return (unsigned int)ha | ((unsigned int)hv << 16);
}
__device__ __forceinline__ float bflo(unsigned int u) {
  return __builtin_bit_cast(float, u << 16);
}
__device__ __forceinline__ float bfhi(unsigned int u) {
  return __builtin_bit_cast(float, u & 0xffff0000u);
}

// ---------------------------------------------------------------------------
// K0: pack Cw [128k x 128d] into bf16 MFMA fragment order.
// ---------------------------------------------------------------------------
__global__ __launch_bounds__(256) void k0_pack(const float* __restrict__ Cw,
                                               __bf16* __restrict__ ws0) {
  int tid = blockIdx.x * 256 + threadIdx.x;  // nt*256 + ks*64 + l
  int l  = tid & 63;
  int nt = tid >> 8;
  int ks = (tid >> 6) & 3;
  int d  = nt * 16 + (l & 15);
  int kb = ks * 32 + (l >> 4) * 8;
  bf16x8 v;
#pragma unroll
  for (int q = 0; q < 8; ++q) v[q] = (__bf16)Cw[(kb + q) * D + d];
  *(bf16x8*)(ws0 + tid * 8) = v;
}

// ---------------------------------------------------------------------------
// K1: Uh/Vh/Ah/(Bh+Cb) = h @ {U,V,A,B}w + bias.  R19: 2 rows per block
// (grid 1024, 4 blocks/CU = 16 waves/CU) -- halves weight L2 traffic while
// keeping latency-hiding concurrency (R18's 8-row/grid-256 collapsed it).
// ---------------------------------------------------------------------------
__global__ __launch_bounds__(256) void k1_lin4(
    const float* __restrict__ h,
    const float* __restrict__ Uw, const float* __restrict__ Ub,
    const float* __restrict__ Vw, const float* __restrict__ Vb,
    const float* __restrict__ Aw, const float* __restrict__ Ab,
    const float* __restrict__ Bw, const float* __restrict__ Bb,
    const float* __restrict__ Cb,
    float* __restrict__ wsU, float* __restrict__ wsB,
    unsigned int* __restrict__ wsAVT, unsigned int* __restrict__ wsAVR) {
  __shared__ float hrow[2][128];
  __shared__ float exA[2][128];
  __shared__ float exV[2][128];
  const int rbase = blockIdx.x * 2;
  const int t = threadIdx.x;
  {
    int rr = t >> 7, dd = t & 127;
    hrow[rr][dd] = h[(rbase + rr) * D + dd];
  }
  __syncthreads();
  const int d = t & 127;
  const bool lo = (t < 128);
  const float* W0 = lo ? Uw : Vw;
  const float* W1m = lo ? Aw : Bw;
  const float base0 = (lo ? Ub : Vb)[d];
  const float base1 = lo ? Ab[d] : (Bb[d] + Cb[d]);
  float a0[2], a1[2];
#pragma unroll
  for (int r = 0; r < 2; ++r) { a0[r] = base0; a1[r] = base1; }
#pragma unroll 4
  for (int k = 0; k < D; ++k) {
    float w0v = W0[k * D + d];
    float w1v = W1m[k * D + d];
#pragma unroll
    for (int r = 0; r < 2; ++r) {
      float hk = hrow[r][k];
      a0[r] = fmaf(hk, w0v, a0[r]);
      a1[r] = fmaf(hk, w1v, a1[r]);
    }
  }
#pragma unroll
  for (int r = 0; r < 2; ++r) {
    int row = rbase + r;
    if (lo) {
      wsU[row * D + d] = a0[r];
      exA[r][d] = a1[r];
    } else {
      exV[r][d] = a0[r];
      wsB[row * D + d] = a1[r];
    }
  }
  __syncthreads();
  {
    int rr = t >> 7, dd = t & 127;
    int row = rbase + rr;
    int b = row >> 8, i = row & 255;
    unsigned int p = packbf(exA[rr][dd], exV[rr][dd]);
    wsAVR[row * D + dd] = p;               // row-major
    wsAVT[(b << 15) + dd * NN + i] = p;    // transposed (fallback)
  }
}

// ---------------------------------------------------------------------------
// K2 (big path): PURE GEMM: ws1 = bf16(e @ Cw).  R17-proven: bfr LDS
// staging, stride-66 stW, full-tile 4KB stores, 3 blocks/CU, 2-deep
// e-prefetch (pfA/pfB ping-pong).
// ---------------------------------------------------------------------------
__global__ __launch_bounds__(256, 3) void k_gemm(
    const float* __restrict__ e,
    const __bf16* __restrict__ ws0,
    __bf16* __restrict__ ws1) {
  __shared__ __align__(16) __bf16 bfr[16384];        // 32 KB Cw fragments
  __shared__ __align__(16) unsigned int stW[4224];   // [4][16][66] u32
  const int t = threadIdx.x;
  const int blk = blockIdx.x;

#pragma unroll
  for (int c = 0; c < 8; ++c) {
    int idx = c * 256 + t;
    *(f32x4*)(bfr + idx * 8) = *(const f32x4*)(ws0 + idx * 8);
  }
  __syncthreads();

  const int w = t >> 6;
  const int l = t & 63;
  const int l15 = l & 15;
  const int lhi = l >> 4;
  unsigned int* stWu = stW + w * 1056;  // [16][66]

  const float* eblk = e + (size_t)blk * (NN * D);
  const float* ap = eblk + (w * 64 + l15) * D + lhi * 8;

  // 2-deep prefetch: pfA=tile0, pfB=tile1
  f32x4 pfA[8], pfB[8];
#pragma unroll
  for (int q = 0; q < 8; ++q) pfA[q] = *(const f32x4*)(ap + (q >> 1) * 32 + (q & 1) * 4);
#pragma unroll
  for (int q = 0; q < 8; ++q) pfB[q] = *(const f32x4*)(ap + 16 * D + (q >> 1) * 32 + (q & 1) * 4);

  auto do_tile = [&](const f32x4* pf, int mt) {
    bf16x8 af[4];
#pragma unroll
    for (int ks = 0; ks < 4; ++ks) af[ks] = cvt8(pf[2 * ks], pf[2 * ks + 1]);
    const int J0 = w * 64 + mt * 16;
#pragma unroll
    for (int nt = 0; nt < 8; ++nt) {
      f32x4 acc = {0.f, 0.f, 0.f, 0.f};
#pragma unroll
      for (int ks = 0; ks < 4; ++ks) {
        bf16x8 bfrg = *(const bf16x8*)(bfr + ((nt * 4 + ks) * 64 + l) * 8);
        acc = __builtin_amdgcn_mfma_f32_16x16x32_bf16(af[ks], bfrg, acc, 0, 0, 0);
      }
#pragma unroll
      for (int r = 0; r < 4; ++r) {
        float v = acc[r];
        float vp = __shfl_xor(v, 1);  // partner lane holds d^1
        if ((l15 & 1) == 0) {
          stWu[(lhi * 4 + r) * 66 + (nt << 3) + (l15 >> 1)] = packbf(v, vp);
        }
      }
    }
    // coalesced u32 store of the 16x128 bf16 tile (4KB contiguous)
    unsigned int* dstu = (unsigned int*)(ws1 + (size_t)blk * (NN * D) + J0 * D);
#pragma unroll
    for (int i = 0; i < 16; ++i) {
      dstu[i * 64 + l] = stWu[i * 66 + l];
    }
  };

  // tile 0 (pfA), refill pfA <- tile 2
  {
    f32x4 cur[8];
#pragma unroll
    for (int q = 0; q < 8; ++q) cur[q] = pfA[q];
#pragma unroll
    for (int q = 0; q < 8; ++q) pfA[q] = *(const f32x4*)(ap + 32 * D + (q >> 1) * 32 + (q & 1) * 4);
    do_tile(cur, 0);
  }
  // tile 1 (pfB), refill pfB <- tile 3
  {
    f32x4 cur[8];
#pragma unroll
    for (int q = 0; q < 8; ++q) cur[q] = pfB[q];
#pragma unroll
    for (int q = 0; q < 8; ++q) pfB[q] = *(const f32x4*)(ap + 48 * D + (q >> 1) * 32 + (q & 1) * 4);
    do_tile(cur, 1);
  }
  do_tile(pfA, 2);
  do_tile(pfB, 3);
}

// ---------------------------------------------------------------------------
// K2b (big path): streaming stats + gated aggregation from ws1 (R13 form).
// ---------------------------------------------------------------------------
__global__ __launch_bounds__(256) void k_stats(
    const __bf16* __restrict__ ws1,
    const unsigned int* __restrict__ AVR,   // [b*256+j][d] packed Ah|Vh
    const float* __restrict__ Bh2,          // Bh + Cb
    float* __restrict__ wsP) {
  __shared__ float red[16][3][128];
  const int t = threadIdx.x;
  const int blk = blockIdx.x;
  const int b = blk >> 8;
  const int jg = t >> 4;
  const int dg = t & 15;

  float cb[8];
  {
    f32x4 c0 = *(const f32x4*)(Bh2 + blk * D + dg * 8);
    f32x4 c1 = *(const f32x4*)(Bh2 + blk * D + dg * 8 + 4);
#pragma unroll
    for (int q = 0; q < 4; ++q) { cb[q] = c0[q]; cb[4 + q] = c1[q]; }
  }

  float es[8], eq[8], hp[8];
#pragma unroll
  for (int q = 0; q < 8; ++q) { es[q] = 0.f; eq[q] = 0.f; hp[q] = 0.f; }

  const unsigned int* w1 = (const unsigned int*)(ws1 + (size_t)blk * (NN * D));
  const unsigned int* avb = AVR + ((size_t)(b << 8)) * D;

#pragma unroll 1
  for (int k = 0; k < 16; ++k) {
    const int j = k * 16 + jg;
    u32x4 a = *(const u32x4*)(w1 + j * 64 + dg * 4);          // 8 bf16 e_new
    u32x4 av0 = *(const u32x4*)(avb + j * D + dg * 8);        // d0..d3
    u32x4 av1 = *(const u32x4*)(avb + j * D + dg * 8 + 4);    // d4..d7
#pragma unroll
    for (int q = 0; q < 4; ++q) {
      unsigned int avA = (q < 2) ? av0[2 * q] : av1[2 * (q - 2)];
      unsigned int avB = (q < 2) ? av0[2 * q + 1] : av1[2 * (q - 2) + 1];
      float v0 = bflo(a[q]) + cb[2 * q] + bflo(avA);
      float v1 = bfhi(a[q]) + cb[2 * q + 1] + bflo(avB);
      es[2 * q] += v0;
      eq[2 * q] = fmaf(v0, v0, eq[2 * q]);
      hp[2 * q] = fmaf(sigmoid_f(v0), bfhi(avA), hp[2 * q]);
      es[2 * q + 1] += v1;
      eq[2 * q + 1] = fmaf(v1, v1, eq[2 * q + 1]);
      hp[2 * q + 1] = fmaf(sigmoid_f(v1), bfhi(avB), hp[2 * q + 1]);
    }
  }

#pragma unroll
  for (int q = 0; q < 8; ++q) {
    red[jg][0][dg * 8 + q] = es[q];
    red[jg][1][dg * 8 + q] = eq[q];
    red[jg][2][dg * 8 + q] = hp[q];
  }
  __syncthreads();
  if (t < 128) {
    float S = 0.f, Q = 0.f, H = 0.f;
#pragma unroll
    for (int g = 0; g < 16; ++g) {
      S += red[g][0][t];
      Q += red[g][1][t];
      H += red[g][2][t];
    }
    wsP[blk * 384 + t] = S;
    wsP[blk * 384 + 128 + t] = Q;
    wsP[blk * 384 + 256 + t] = H;
  }
}

// ---------------------------------------------------------------------------
// K5 (big path, streaming): out_e = relu(ge*(ws1+cb+ah) + be) + e.
// ---------------------------------------------------------------------------
__global__ __launch_bounds__(256) void k_epass1s(
    const __bf16* __restrict__ ws1,
    const float* __restrict__ e,
    const unsigned int* __restrict__ AVR,
    const float* __restrict__ Bh2,
    const float* __restrict__ ws6,   // [0:128) ge, [128:256) be
    float* __restrict__ out_e) {
  const int tid = blockIdx.x * 256 + threadIdx.x;
  const int d0 = (tid & 15) * 8;
  f32x4 ge0 = *(const f32x4*)(ws6 + d0);
  f32x4 ge1 = *(const f32x4*)(ws6 + d0 + 4);
  f32x4 be0 = *(const f32x4*)(ws6 + 128 + d0);
  f32x4 be1 = *(const f32x4*)(ws6 + 128 + d0 + 4);
#pragma unroll 2
  for (int k = 0; k < 16; ++k) {
    size_t idx = (size_t)tid + (size_t)k * 524288;  // vec8 index
    size_t row = idx >> 4;                 // b*65536 + i*256 + j
    int j = (int)(row & 255);
    int bb = (int)(row >> 16);
    size_t avrow = ((size_t)(bb << 8) + j);
    u32x4 u = *(const u32x4*)(ws1 + idx * 8);
    u32x4 av0 = *(const u32x4*)(AVR + avrow * D + d0);
    u32x4 av1 = *(const u32x4*)(AVR + avrow * D + d0 + 4);
    const float* cbp = Bh2 + (row >> 8) * D + d0;
    f32x4 c0 = *(const f32x4*)cbp;
    f32x4 c1 = *(const f32x4*)(cbp + 4);
    const float* ep = e + idx * 8;
    f32x4 e0 = *(const f32x4*)ep;
    f32x4 e1 = *(const f32x4*)(ep + 4);
    f32x4 o0, o1;
#pragma unroll
    for (int q = 0; q < 2; ++q) {
      float v0 = bflo(u[q]) + c0[2 * q] + bflo(av0[2 * q]);
      float v1 = bfhi(u[q]) + c0[2 * q + 1] + bflo(av0[2 * q + 1]);
      o0[2 * q]     = fmaxf(fmaf(v0, ge0[2 * q], be0[2 * q]), 0.f) + e0[2 * q];
      o0[2 * q + 1] = fmaxf(fmaf(v1, ge0[2 * q + 1], be0[2 * q + 1]), 0.f) + e0[2 * q + 1];
      float v2 = bflo(u[2 + q]) + c1[2 * q] + bflo(av1[2 * q]);
      float v3 = bfhi(u[2 + q]) + c1[2 * q + 1] + bflo(av1[2 * q + 1]);
      o1[2 * q]     = fmaxf(fmaf(v2, ge1[2 * q], be1[2 * q]), 0.f) + e1[2 * q];
      o1[2 * q + 1] = fmaxf(fmaf(v3, ge1[2 * q + 1], be1[2 * q + 1]), 0.f) + e1[2 * q + 1];
    }
    float* op = out_e + idx * 8;
    *(f32x4*)op = o0;
    *(f32x4*)(op + 4) = o1;
  }
}

// ---------------------------------------------------------------------------
// FALLBACK kernels (small ws): fused epass0 + recompute epass1 (AVT layout).
// ---------------------------------------------------------------------------
__global__ __launch_bounds__(256, 3) void k_epass0_fused(
    const float* __restrict__ e,
    const __bf16* __restrict__ ws0,
    const unsigned int* __restrict__ AVT,
    const float* __restrict__ Bh2,
    float* __restrict__ wsP) {
  __shared__ __align__(16) __bf16 bfr[16384];
  __shared__ __align__(16) unsigned int uni32[4224];
  const int t = threadIdx.x;
  const int blk = blockIdx.x;
  const int b = blk >> 8;

#pragma unroll
  for (int c = 0; c < 8; ++c) {
    int idx = c * 256 + t;
    *(f32x4*)(bfr + idx * 8) = *(const f32x4*)(ws0 + idx * 8);
  }
  __syncthreads();

  const int w = t >> 6;
  const int l = t & 63;
  const int l15 = l & 15;
  const int lhi = l >> 4;

  float cbias[8];
#pragma unroll
  for (int nt = 0; nt < 8; ++nt) cbias[nt] = Bh2[blk * D + nt * 16 + l15];

  float es[8], eq[8], hp[8];
#pragma unroll
  for (int nt = 0; nt < 8; ++nt) { es[nt] = 0.f; eq[nt] = 0.f; hp[nt] = 0.f; }

  const float* eblk = e + (size_t)blk * (NN * D);
  const unsigned int* AVb = AVT + ((size_t)b << 15);

  const float* ap = eblk + (w * 64 + l15) * D + lhi * 8;
  f32x4 pf[8];
#pragma unroll
  for (int q = 0; q < 8; ++q) pf[q] = *(const f32x4*)(ap + (q >> 1) * 32 + (q & 1) * 4);

#pragma unroll 1
  for (int mt = 0; mt < 4; ++mt) {
    bf16x8 af[4];
#pragma unroll
    for (int ks = 0; ks < 4; ++ks) af[ks] = cvt8(pf[2 * ks], pf[2 * ks + 1]);
    if (mt < 3) {
      const float* ap2 = ap + (mt + 1) * 16 * D;
#pragma unroll
      for (int q = 0; q < 8; ++q) pf[q] = *(const f32x4*)(ap2 + (q >> 1) * 32 + (q & 1) * 4);
    }
    const int J0 = w * 64 + mt * 16;
#pragma unroll
    for (int nt = 0; nt < 8; ++nt) {
      f32x4 acc = {0.f, 0.f, 0.f, 0.f};
#pragma unroll
      for (int ks = 0; ks < 4; ++ks) {
        bf16x8 bfrg = *(const bf16x8*)(bfr + ((nt * 4 + ks) * 64 + l) * 8);
        acc = __builtin_amdgcn_mfma_f32_16x16x32_bf16(af[ks], bfrg, acc, 0, 0, 0);
      }
      const int doff = (nt * 16 + l15) * NN + J0 + lhi * 4;
      u32x4 uv = *(const u32x4*)(AVb + doff);
#pragma unroll
      for (int r = 0; r < 4; ++r) {
        float v = acc[r] + cbias[nt] + bflo(uv[r]);
        es[nt] += v;
        eq[nt] = fmaf(v, v, eq[nt]);
        float g = sigmoid_f(v);
        hp[nt] = fmaf(g, bfhi(uv[r]), hp[nt]);
      }
    }
  }

#pragma unroll
  for (int nt = 0; nt < 8; ++nt) {
    es[nt] += __shfl_xor(es[nt], 16); es[nt] += __shfl_xor(es[nt], 32);
    eq[nt] += __shfl_xor(eq[nt], 16); eq[nt] += __shfl_xor(eq[nt], 32);
    hp[nt] += __shfl_xor(hp[nt], 16); hp[nt] += __shfl_xor(hp[nt], 32);
  }
  __syncthreads();
  float* red = (float*)uni32;
  if (l < 16) {
#pragma unroll
    for (int nt = 0; nt < 8; ++nt) {
      red[(w * 3 + 0) * 128 + nt * 16 + l] = es[nt];
      red[(w * 3 + 1) * 128 + nt * 16 + l] = eq[nt];
      red[(w * 3 + 2) * 128 + nt * 16 + l] = hp[nt];
    }
  }
  __syncthreads();
  if (t < 128) {
    float S = red[0 * 128 + t] + red[3 * 128 + t] + red[6 * 128 + t] + red[9 * 128 + t];
    float Q = red[1 * 128 + t] + red[4 * 128 + t] + red[7 * 128 + t] + red[10 * 128 + t];
    float H = red[2 * 128 + t] + red[5 * 128 + t] + red[8 * 128 + t] + red[11 * 128 + t];
    wsP[blk * 384 + t] = S;
    wsP[blk * 384 + 128 + t] = Q;
    wsP[blk * 384 + 256 + t] = H;
  }
}

__global__ __launch_bounds__(256, 3) void k_epass1(
    const float* __restrict__ e,
    const __bf16* __restrict__ ws0,
    const unsigned int* __restrict__ AVT,
    const float* __restrict__ Bh2,
    const float* __restrict__ ws6,
    float* __restrict__ out_e) {
  __shared__ __align__(16) __bf16 bfr[16384];
  __shared__ float st[4][16 * 68];
  const int t = threadIdx.x;
  const int blk = blockIdx.x;
  const int b = blk >> 8;

#pragma unroll
  for (int c = 0; c < 8; ++c) {
    int idx = c * 256 + t;
    *(f32x4*)(bfr + idx * 8) = *(const f32x4*)(ws0 + idx * 8);
  }
  __syncthreads();

  const int w = t >> 6;
  const int l = t & 63;
  const int l15 = l & 15;
  const int lhi = l >> 4;
  float* stw = &st[w][0];

  float cbias[8], ge[8], be[8];
#pragma unroll
  for (int nt = 0; nt < 8; ++nt) {
    int d = nt * 16 + l15;
    cbias[nt] = Bh2[blk * D + d];
    ge[nt] = ws6[d];
    be[nt] = ws6[128 + d];
  }

  const float* eblk = e + (size_t)blk * (NN * D);
  const unsigned int* AVb = AVT + ((size_t)b << 15);
  float* outB = out_e + (size_t)blk * (NN * D);

  const int srow = l >> 4;
  const int scol = (l & 15) * 4;

  const float* ap = eblk + (w * 64 + l15) * D + lhi * 8;
  f32x4 pf[8];
#pragma unroll
  for (int q = 0; q < 8; ++q) pf[q] = *(const f32x4*)(ap + (q >> 1) * 32 + (q & 1) * 4);

#pragma unroll 1
  for (int mt = 0; mt < 4; ++mt) {
    bf16x8 af[4];
#pragma unroll
    for (int ks = 0; ks < 4; ++ks) af[ks] = cvt8(pf[2 * ks], pf[2 * ks + 1]);
    if (mt < 3) {
      const float* ap2 = ap + (mt + 1) * 16 * D;
#pragma unroll
      for (int q = 0; q < 8; ++q) pf[q] = *(const f32x4*)(ap2 + (q >> 1) * 32 + (q & 1) * 4);
    }
    const int J0 = w * 64 + mt * 16;
#pragma unroll
    for (int p = 0; p < 2; ++p) {
#pragma unroll
      for (int ntl = 0; ntl < 4; ++ntl) {
        const int nt = p * 4 + ntl;
        f32x4 acc = {0.f, 0.f, 0.f, 0.f};
#pragma unroll
        for (int ks = 0; ks < 4; ++ks) {
          bf16x8 bfrg = *(const bf16x8*)(bfr + ((nt * 4 + ks) * 64 + l) * 8);
          acc = __builtin_amdgcn_mfma_f32_16x16x32_bf16(af[ks], bfrg, acc, 0, 0, 0);
        }
        const int doff = (nt * 16 + l15) * NN + J0 + lhi * 4;
        u32x4 uv = *(const u32x4*)(AVb + doff);
#pragma unroll
        for (int r = 0; r < 4; ++r) {
          float v = acc[r] + cbias[nt] + bflo(uv[r]);
          stw[(lhi * 4 + r) * 68 + ntl * 16 + l15] =
              fmaxf(fmaf(v, ge[nt], be[nt]), 0.0f);
        }
      }
#pragma unroll
      for (int it = 0; it < 4; ++it) {
        const int row = it * 4 + srow;
        const int goff = (J0 + row) * D + p * 64 + scol;
        f32x4 res = *(const f32x4*)(eblk + goff);
        f32x4 q = *(const f32x4*)(stw + row * 68 + scol);
        *(f32x4*)(outB + goff) = q + res;
      }
    }
  }
}

// ---------------------------------------------------------------------------
// K3a: stage-1 reduce of block partials and h_new = Uh + hsum (to ws7).
// ---------------------------------------------------------------------------
__global__ __launch_bounds__(256) void k3a(const float* __restrict__ wsP,
                                           const float* __restrict__ wsU,
                                           float* __restrict__ ws7,
                                           float* __restrict__ wsPB) {
  __shared__ float red2[2][4][128];
  int t = threadIdx.x, blk = blockIdx.x;
  int c = t & 127, half = t >> 7;
  float es = 0.f, eq = 0.f, hs = 0.f, hq = 0.f;
  for (int s = 0; s < 16; ++s) {
    int row = blk * 32 + half * 16 + s;
    es += wsP[row * 384 + c];
    eq += wsP[row * 384 + 128 + c];
    float v = wsU[row * D + c] + wsP[row * 384 + 256 + c];
    ws7[row * D + c] = v;
    hs += v;
    hq = fmaf(v, v, hq);
  }
  red2[half][0][c] = es; red2[half][1][c] = eq;
  red2[half][2][c] = hs; red2[half][3][c] = hq;
  __syncthreads();
  if (t < 128) {
#pragma unroll
    for (int k = 0; k < 4; ++k)
      wsPB[blk * 512 + k * 128 + t] = red2[0][k][t] + red2[1][k][t];
  }
}

// K3b: final stats -> affine coefficients.
__global__ __launch_bounds__(256) void k3b(const float* __restrict__ wsPB,
                                           const float* __restrict__ gamma_e,
                                           const float* __restrict__ beta_e,
                                           const float* __restrict__ gamma_h,
                                           const float* __restrict__ beta_h,
                                           float* __restrict__ ws6) {
  int t = threadIdx.x;
  int c = t & 127, g = t >> 7;
  float S = 0.f, Q = 0.f;
  for (int blk = 0; blk < 64; ++blk) {
    S += wsPB[blk * 512 + (g * 2) * 128 + c];
    Q += wsPB[blk * 512 + (g * 2 + 1) * 128 + c];
  }
  float M = g ? 2048.0f : 524288.0f;
  float mean = S / M;
  float var = Q / M - mean * mean;
  float rstd = rsqrtf(var + 1e-5f);
  float gam = (g ? gamma_h : gamma_e)[c] * rstd;
  float bet = (g ? beta_h : beta_e)[c] - mean * gam;
  ws6[g * 256 + c] = gam;
  ws6[g * 256 + 128 + c] = bet;
}

// ---------------------------------------------------------------------------
// K4: h-side: BN_h, MLP (gelu), residual.  R19: 2 rows per block (grid
// 1024) -- halves W1/W2 L2 traffic, keeps 16 waves/CU; phase 2 uses all
// 256 threads (2 rows x 128 d).
// ---------------------------------------------------------------------------
__global__ __launch_bounds__(256) void k4_mlp(
    const float* __restrict__ ws7, const float* __restrict__ ws6,
    const float* __restrict__ W1, const float* __restrict__ b1,
    const float* __restrict__ W2, const float* __restrict__ b2,
    const float* __restrict__ h_in, float* __restrict__ out_h) {
  __shared__ float hn[2][128];
  __shared__ float t1[2][FF];
  const int rbase = blockIdx.x * 2;
  const int t = threadIdx.x;
  {
    int rr = t >> 7, dd = t & 127;
    float v = ws7[(rbase + rr) * D + dd];
    hn[rr][dd] = fmaf(v, ws6[256 + dd], ws6[384 + dd]);
  }
  __syncthreads();
  {
    const int f0 = t, f1 = t + 256;
    float a0[2], a1[2];
    const float bb0 = b1[f0], bb1 = b1[f1];
#pragma unroll
    for (int r = 0; r < 2; ++r) { a0[r] = bb0; a1[r] = bb1; }
#pragma unroll 4
    for (int k = 0; k < D; ++k) {
      float w0 = W1[k * FF + f0];
      float w1 = W1[k * FF + f1];
#pragma unroll
      for (int r = 0; r < 2; ++r) {
        float hk = hn[r][k];
        a0[r] = fmaf(hk, w0, a0[r]);
        a1[r] = fmaf(hk, w1, a1[r]);
      }
    }
#pragma unroll
    for (int r = 0; r < 2; ++r) {
      t1[r][f0] = gelu_f(a0[r]);
      t1[r][f1] = gelu_f(a1[r]);
    }
  }
  __syncthreads();
  {
    const int d = t & 127;
    const int r = t >> 7;  // 0 or 1
    float acc = b2[d];
#pragma unroll 4
    for (int k = 0; k < FF; ++k) acc = fmaf(t1[r][k], W2[k * D + d], acc);
    int row = rbase + r;
    out_h[row * D + d] = h_in[row * D + d] + acc;
  }
}

// ---------------------------------------------------------------------------
extern "C" void kernel_launch(void* const* d_in, const int* in_sizes, int n_in,
                              void* d_out, int out_size, void* d_ws, size_t ws_size,
                              hipStream_t stream) {
  (void)in_sizes; (void)n_in; (void)out_size;
  const float* h       = (const float*)d_in[0];
  const float* e       = (const float*)d_in[1];
  const float* Uw      = (const float*)d_in[2];
  const float* Ub      = (const float*)d_in[3];
  const float* Vw      = (const float*)d_in[4];
  const float* Vb      = (const float*)d_in[5];
  const float* Aw      = (const float*)d_in[6];
  const float* Ab      = (const float*)d_in[7];
  const float* Bw      = (const float*)d_in[8];
  const float* Bb      = (const float*)d_in[9];
  const float* Cw      = (const float*)d_in[10];
  const float* Cb      = (const float*)d_in[11];
  const float* gamma_h = (const float*)d_in[12];
  const float* beta_h  = (const float*)d_in[13];
  const float* gamma_e = (const float*)d_in[14];
  const float* beta_e  = (const float*)d_in[15];
  const float* W1      = (const float*)d_in[16];
  const float* b1      = (const float*)d_in[17];
  const float* W2      = (const float*)d_in[18];
  const float* b2      = (const float*)d_in[19];

  float* ws   = (float*)d_ws;
  __bf16* ws0 = (__bf16*)ws;                 // 16384 bf16 (8192 f32 slots)
  float* wsU  = ws + 8192;
  float* wsB  = wsU + NB * D;                // Bh + Cb
  unsigned int* wsAVT = (unsigned int*)(wsB + NB * D);   // [b][d][j]
  unsigned int* wsAVR = wsAVT + NB * D;                  // [b*256+j][d]
  float* wsP  = (float*)(wsAVR + NB * D);    // 2048 * 384
  float* wsPB = wsP + NB * 384;              // 64 * 512
  float* ws6  = wsPB + 64 * 512;             // 512 affine coeffs
  float* ws7  = ws6 + 512;                   // h_new 2048*128
  size_t head_bytes = (size_t)(ws7 + NB * D - ws) * 4;
  head_bytes = (head_bytes + 255) & ~(size_t)255;
  __bf16* ws1 = (__bf16*)((char*)d_ws + head_bytes);
  size_t need = head_bytes + (size_t)NB * NN * D * 2;
  bool big = (ws_size >= need);

  float* out_h = (float*)d_out;
  float* out_e = out_h + NB * D;

  k0_pack<<<dim3(8), dim3(256), 0, stream>>>(Cw, ws0);
  k1_lin4<<<dim3(NB / 2), dim3(256), 0, stream>>>(h, Uw, Ub, Vw, Vb, Aw, Ab, Bw, Bb,
                                                  Cb, wsU, wsB, wsAVT, wsAVR);
  if (big) {
    k_gemm<<<dim3(NB), dim3(256), 0, stream>>>(e, ws0, ws1);
    k_stats<<<dim3(NB), dim3(256), 0, stream>>>(ws1, wsAVR, wsB, wsP);
  } else {
    k_epass0_fused<<<dim3(NB), dim3(256), 0, stream>>>(e, ws0, wsAVT, wsB, wsP);
  }
  k3a<<<dim3(64), dim3(256), 0, stream>>>(wsP, wsU, ws7, wsPB);
  k3b<<<dim3(1), dim3(256), 0, stream>>>(wsPB, gamma_e, beta_e, gamma_h, beta_h, ws6);
  k4_mlp<<<dim3(NB / 2), dim3(256), 0, stream>>>(ws7, ws6, W1, b1, W2, b2, h, out_h);
  if (big) {
    k_epass1s<<<dim3(2048), dim3(256), 0, stream>>>(ws1, e, wsAVR, wsB, ws6, out_e);
  } else {
    k_epass1<<<dim3(NB), dim3(256), 0, stream>>>(e, ws0, wsAVT, wsB, ws6, out_e);
  }
}